// Round 6
// baseline (356.617 us; speedup 1.0000x reference)
//
#include <hip/hip_runtime.h>

// ---------------------------------------------------------------------------
// 2-layer GCN + LayerNorm on MI355X (gfx950), bf16 MFMA GEMMs.
//   Graph build via per-dst linked list (1 atomic/edge), fused walks+scan.
//   Layer 1 aggregate-first:  ax = A_norm @ x_bf16   -> out1 = relu(ax@W1+b1)
//   Layer 2 transform-first:  h2 = out1 @ W2 (bf16)  -> y = agg(h2)+b2
//                             out = LN(y)*gamma+beta (separate streaming pass)
//   Aggregation is FEATURE-SLICED into 4 passes of 32 cols (64 B = 1 line):
//   slice working set = 3.2 MB < 4 MB per-XCD L2 -> gathers become L2 hits.
//   Pass-major block order (pass = blockIdx.x / bpp) keeps one slice resident.
//   Per wave: one (node, pass); 16 lanes per edge, 4 edges per instruction.
// ---------------------------------------------------------------------------

#define TPB 256

typedef __bf16 bf16;
typedef __bf16 bf16x2 __attribute__((ext_vector_type(2)));
typedef __bf16 bf16x4 __attribute__((ext_vector_type(4)));
typedef __bf16 bf16x8 __attribute__((ext_vector_type(8)));
typedef float  f32x4  __attribute__((ext_vector_type(4)));

// ---- prep: head=-1, x->bf16 (float4 granules), W1^T, W2^T (bf16) ----------
__global__ void k_prep(const float* __restrict__ x, bf16* __restrict__ x_bf,
                       const float* __restrict__ W1, bf16* __restrict__ W1T,
                       const float* __restrict__ W2, bf16* __restrict__ W2T,
                       int* __restrict__ head, int N, int n4, int nw,
                       int D, int H) {
  int i = blockIdx.x * TPB + threadIdx.x;
  if (i < N) head[i] = -1;
  if (i < nw) {
    int r1 = i / H, c1 = i % H;          // W1 [D][H] -> W1T [H][D]
    W1T[(size_t)c1 * D + r1] = (bf16)W1[i];
    int r2 = i / D, c2 = i % D;          // W2 [H][D] -> W2T [D][H]
    W2T[(size_t)c2 * H + r2] = (bf16)W2[i];
  }
  if (i < n4) {
    float4 v = reinterpret_cast<const float4*>(x)[i];
    bf16x4 o;
    o.x = (bf16)v.x; o.y = (bf16)v.y; o.z = (bf16)v.z; o.w = (bf16)v.w;
    reinterpret_cast<bf16x4*>(x_bf)[i] = o;
  }
}

__global__ void k_link(const int* __restrict__ dst, int* head,
                       int* __restrict__ next, int E) {
  int e = blockIdx.x * TPB + threadIdx.x;
  if (e < E) next[e] = atomicExch(&head[dst[e]], e);
}

// walk list: deg = 1 + sum(ew) -> dinv, cnt; fused per-block reduce -> bsum
__global__ void k_walk_deg(const int* __restrict__ head, const int* __restrict__ next,
                           const float* __restrict__ ew, float* __restrict__ dinv,
                           int* __restrict__ cnt, int* __restrict__ bsum, int N) {
  __shared__ int sm[TPB];
  int i = blockIdx.x * TPB + threadIdx.x;
  int c = 0;
  if (i < N) {
    float d = 1.0f;   // self-loop weight
    int h = head[i];
    while (h >= 0) {
      d += ew[h];
      ++c;
      h = next[h];
    }
    dinv[i] = rsqrtf(d);
    cnt[i] = c;
  }
  sm[threadIdx.x] = c;
  __syncthreads();
  for (int s = TPB / 2; s > 0; s >>= 1) {
    if (threadIdx.x < s) sm[threadIdx.x] += sm[threadIdx.x + s];
    __syncthreads();
  }
  if (threadIdx.x == 0) bsum[blockIdx.x] = sm[0];
}

__global__ void k_scan_bsums(const int* __restrict__ bsum, int* bscan, int nb) {
  __shared__ int sm[TPB];
  int t = threadIdx.x;
  int v = (t < nb) ? bsum[t] : 0;
  sm[t] = v;
  __syncthreads();
  for (int off = 1; off < TPB; off <<= 1) {
    int add = (t >= off) ? sm[t - off] : 0;
    __syncthreads();
    sm[t] += add;
    __syncthreads();
  }
  if (t < nb) bscan[t] = sm[t] - v;   // exclusive
}

// in-block scan of cnt -> row_ptr, then walk list filling {src, norm}
__global__ void k_scan_fill(const int* __restrict__ cnt, const int* __restrict__ bscan,
                            const int* __restrict__ head, const int* __restrict__ next,
                            const int* __restrict__ src, const float* __restrict__ ew,
                            const float* __restrict__ dinv,
                            int* __restrict__ row_ptr, int2* __restrict__ csr, int N) {
  __shared__ int sm[TPB];
  int t = threadIdx.x;
  int i = blockIdx.x * TPB + t;
  int v = (i < N) ? cnt[i] : 0;
  sm[t] = v;
  __syncthreads();
  for (int off = 1; off < TPB; off <<= 1) {
    int add = (t >= off) ? sm[t - off] : 0;
    __syncthreads();
    sm[t] += add;
    __syncthreads();
  }
  if (i < N) {
    int pos = bscan[blockIdx.x] + sm[t] - v;
    row_ptr[i] = pos;
    float di = dinv[i];
    int h = head[i];
    while (h >= 0) {
      int s = src[h];
      csr[pos++] = make_int2(s, __float_as_int(dinv[s] * ew[h] * di));
      h = next[h];
    }
  }
}

// ---- bf16 MFMA GEMM, no LDS: C[M,NC] = A[M,K] @ BT[NC,K]^T (+bias,+relu) --
// Block: 256 thr / 4 waves; BM=128 (wave w: rows 32w..32w+31), BN=64.
// Frag layout (16x16x32): elem j of lane l -> k = 8*(l>>4)+j, m/n = l&15.
// C/D: col = l&15, row = 4*(l>>4)+reg  [m89-verified].
__global__ __launch_bounds__(256) void k_gemm_mfma(
    const bf16* __restrict__ A, const bf16* __restrict__ BT,
    const float* __restrict__ bias, int relu, int M, int K, int NC,
    bf16* __restrict__ Cb) {
  const int l = threadIdx.x & 63, w = threadIdx.x >> 6;
  const int c = l & 15, g = l >> 4;
  const int m0 = blockIdx.x * 128 + w * 32;
  const int n0 = blockIdx.y * 64;

  int ra0 = m0 + c;       if (ra0 >= M) ra0 = M - 1;
  int ra1 = m0 + 16 + c;  if (ra1 >= M) ra1 = M - 1;
  const bf16* pa0 = A + (size_t)ra0 * K + g * 8;
  const bf16* pa1 = A + (size_t)ra1 * K + g * 8;
  const bf16* pb0 = BT + (size_t)(n0 + c) * K + g * 8;

  f32x4 acc[2][4] = {};
  for (int k0 = 0; k0 < K; k0 += 32) {
    bf16x8 a0 = *reinterpret_cast<const bf16x8*>(pa0 + k0);
    bf16x8 a1 = *reinterpret_cast<const bf16x8*>(pa1 + k0);
    bf16x8 b0 = *reinterpret_cast<const bf16x8*>(pb0 + k0);
    bf16x8 b1 = *reinterpret_cast<const bf16x8*>(pb0 + (size_t)16 * K + k0);
    bf16x8 b2 = *reinterpret_cast<const bf16x8*>(pb0 + (size_t)32 * K + k0);
    bf16x8 b3 = *reinterpret_cast<const bf16x8*>(pb0 + (size_t)48 * K + k0);
    acc[0][0] = __builtin_amdgcn_mfma_f32_16x16x32_bf16(a0, b0, acc[0][0], 0, 0, 0);
    acc[1][0] = __builtin_amdgcn_mfma_f32_16x16x32_bf16(a1, b0, acc[1][0], 0, 0, 0);
    acc[0][1] = __builtin_amdgcn_mfma_f32_16x16x32_bf16(a0, b1, acc[0][1], 0, 0, 0);
    acc[1][1] = __builtin_amdgcn_mfma_f32_16x16x32_bf16(a1, b1, acc[1][1], 0, 0, 0);
    acc[0][2] = __builtin_amdgcn_mfma_f32_16x16x32_bf16(a0, b2, acc[0][2], 0, 0, 0);
    acc[1][2] = __builtin_amdgcn_mfma_f32_16x16x32_bf16(a1, b2, acc[1][2], 0, 0, 0);
    acc[0][3] = __builtin_amdgcn_mfma_f32_16x16x32_bf16(a0, b3, acc[0][3], 0, 0, 0);
    acc[1][3] = __builtin_amdgcn_mfma_f32_16x16x32_bf16(a1, b3, acc[1][3], 0, 0, 0);
  }

#pragma unroll
  for (int mi = 0; mi < 2; ++mi) {
    int rbase = m0 + mi * 16 + g * 4;
#pragma unroll
    for (int ni = 0; ni < 4; ++ni) {
      int col = n0 + ni * 16 + c;
      float bv = bias ? bias[col] : 0.0f;
      f32x4 v = acc[mi][ni];
#pragma unroll
      for (int r = 0; r < 4; ++r) {
        int row = rbase + r;
        if (row < M) {
          float o = v[r] + bv;
          if (relu) o = fmaxf(o, 0.0f);
          Cb[(size_t)row * NC + col] = (bf16)o;
        }
      }
    }
  }
}

// ---- sliced agg layer 1: wave = (node, 32-col slice); 16 lanes per edge ---
__global__ __launch_bounds__(256) void k_agg1_slice(
    const bf16* __restrict__ h, const float* __restrict__ dinv,
    const int* __restrict__ row_ptr, const int* __restrict__ cnt,
    const int2* __restrict__ csr, bf16* __restrict__ out, int N, int bpp) {
  int wid = threadIdx.x >> 6, lane = threadIdx.x & 63;
  int pass = blockIdx.x / bpp, nb = blockIdx.x % bpp;
  int node = nb * 4 + wid;
  if (node >= N) return;
  int q = lane >> 4;                 // edge sub-slot 0..3
  int c = (lane & 15) << 1;          // col pair within slice
  const bf16* hp = h + pass * 32 + c;
  float a0 = 0.f, a1 = 0.f;
  float di = dinv[node];
  if (q == 0) {
    float sw = di * di;
    bf16x2 hv = *reinterpret_cast<const bf16x2*>(hp + (size_t)node * 128);
    a0 = sw * (float)hv.x; a1 = sw * (float)hv.y;
  }
  const int2* cp = csr + row_ptr[node];
  int n = cnt[node];
  for (int j = 0; j < n; j += 8) {
    int i0 = j + q, i1 = j + 4 + q;
    int2 e0 = cp[i0 < n ? i0 : 0];
    int2 e1 = cp[i1 < n ? i1 : 0];
    float w0 = (i0 < n) ? __int_as_float(e0.y) : 0.f;
    float w1 = (i1 < n) ? __int_as_float(e1.y) : 0.f;
    bf16x2 v0 = *reinterpret_cast<const bf16x2*>(hp + (size_t)e0.x * 128);
    bf16x2 v1 = *reinterpret_cast<const bf16x2*>(hp + (size_t)e1.x * 128);
    a0 += w0 * (float)v0.x + w1 * (float)v1.x;
    a1 += w0 * (float)v0.y + w1 * (float)v1.y;
  }
  a0 += __shfl_xor(a0, 16, 64); a0 += __shfl_xor(a0, 32, 64);
  a1 += __shfl_xor(a1, 16, 64); a1 += __shfl_xor(a1, 32, 64);
  if (lane < 16) {
    bf16x2 o; o.x = (bf16)a0; o.y = (bf16)a1;
    *reinterpret_cast<bf16x2*>(out + (size_t)node * 128 + pass * 32 + c) = o;
  }
}

// ---- sliced agg layer 2: + bias; writes y (bf16) + per-slice (s, ss) ------
__global__ __launch_bounds__(256) void k_agg2_slice(
    const bf16* __restrict__ h, const float* __restrict__ dinv,
    const int* __restrict__ row_ptr, const int* __restrict__ cnt,
    const int2* __restrict__ csr, const float* __restrict__ b2,
    bf16* __restrict__ y, float2* __restrict__ stats, int N, int bpp) {
  int wid = threadIdx.x >> 6, lane = threadIdx.x & 63;
  int pass = blockIdx.x / bpp, nb = blockIdx.x % bpp;
  int node = nb * 4 + wid;
  if (node >= N) return;
  int q = lane >> 4;
  int c = (lane & 15) << 1;
  const bf16* hp = h + pass * 32 + c;
  float a0 = 0.f, a1 = 0.f;
  float di = dinv[node];
  if (q == 0) {
    float sw = di * di;
    float2 bb = *reinterpret_cast<const float2*>(b2 + pass * 32 + c);
    bf16x2 hv = *reinterpret_cast<const bf16x2*>(hp + (size_t)node * 128);
    a0 = bb.x + sw * (float)hv.x; a1 = bb.y + sw * (float)hv.y;
  }
  const int2* cp = csr + row_ptr[node];
  int n = cnt[node];
  for (int j = 0; j < n; j += 8) {
    int i0 = j + q, i1 = j + 4 + q;
    int2 e0 = cp[i0 < n ? i0 : 0];
    int2 e1 = cp[i1 < n ? i1 : 0];
    float w0 = (i0 < n) ? __int_as_float(e0.y) : 0.f;
    float w1 = (i1 < n) ? __int_as_float(e1.y) : 0.f;
    bf16x2 v0 = *reinterpret_cast<const bf16x2*>(hp + (size_t)e0.x * 128);
    bf16x2 v1 = *reinterpret_cast<const bf16x2*>(hp + (size_t)e1.x * 128);
    a0 += w0 * (float)v0.x + w1 * (float)v1.x;
    a1 += w0 * (float)v0.y + w1 * (float)v1.y;
  }
  a0 += __shfl_xor(a0, 16, 64); a0 += __shfl_xor(a0, 32, 64);
  a1 += __shfl_xor(a1, 16, 64); a1 += __shfl_xor(a1, 32, 64);
  // per-slice stats (sum, sumsq) over 32 cols
  float s = a0 + a1;
  float ss = a0 * a0 + a1 * a1;
  s  += __shfl_xor(s, 1, 64);  ss += __shfl_xor(ss, 1, 64);
  s  += __shfl_xor(s, 2, 64);  ss += __shfl_xor(ss, 2, 64);
  s  += __shfl_xor(s, 4, 64);  ss += __shfl_xor(ss, 4, 64);
  s  += __shfl_xor(s, 8, 64);  ss += __shfl_xor(ss, 8, 64);
  if (lane < 16) {
    bf16x2 o; o.x = (bf16)a0; o.y = (bf16)a1;
    *reinterpret_cast<bf16x2*>(y + (size_t)node * 128 + pass * 32 + c) = o;
  }
  if (lane == 0) stats[node * 4 + pass] = make_float2(s, ss);
}

// ---- final LayerNorm: streaming over y + stats -> fp32 out ----------------
__global__ __launch_bounds__(256) void k_ln(
    const bf16* __restrict__ y, const float2* __restrict__ stats,
    const float* __restrict__ gamma, const float* __restrict__ beta,
    float* __restrict__ out, int N) {
  int node = blockIdx.x * 4 + (threadIdx.x >> 6);
  if (node >= N) return;
  int c2 = (threadIdx.x & 63) << 1;
  float2 st0 = stats[node * 4 + 0], st1 = stats[node * 4 + 1];
  float2 st2 = stats[node * 4 + 2], st3 = stats[node * 4 + 3];
  float s  = st0.x + st1.x + st2.x + st3.x;
  float ss = st0.y + st1.y + st2.y + st3.y;
  float mu  = s * (1.0f / 128.0f);
  float var = ss * (1.0f / 128.0f) - mu * mu;
  float inv = rsqrtf(var + 1e-5f);
  bf16x2 v = *reinterpret_cast<const bf16x2*>(y + (size_t)node * 128 + c2);
  float2 g  = *reinterpret_cast<const float2*>(gamma + c2);
  float2 be = *reinterpret_cast<const float2*>(beta + c2);
  float2 o;
  o.x = ((float)v.x - mu) * inv * g.x + be.x;
  o.y = ((float)v.y - mu) * inv * g.y + be.y;
  *reinterpret_cast<float2*>(out + (size_t)node * 128 + c2) = o;
}

extern "C" void kernel_launch(void* const* d_in, const int* in_sizes, int n_in,
                              void* d_out, int out_size, void* d_ws, size_t ws_size,
                              hipStream_t stream) {
  const float* x     = (const float*)d_in[0];
  const int*   ei    = (const int*)d_in[1];
  const float* ew    = (const float*)d_in[2];
  const float* W1    = (const float*)d_in[3];
  const float* b1    = (const float*)d_in[4];
  const float* W2    = (const float*)d_in[5];
  const float* b2    = (const float*)d_in[6];
  const float* gamma = (const float*)d_in[7];
  const float* beta  = (const float*)d_in[8];
  float* out = (float*)d_out;

  const int D = 128, H = 256;
  const int N = in_sizes[0] / D;       // 50000
  const int E = in_sizes[2];           // 800000
  const int* src = ei;
  const int* dst = ei + E;

  // workspace carve-up (256B aligned)
  char* p = (char*)d_ws;
  auto carve = [&](size_t bytes) -> void* {
    void* r = (void*)p;
    p += (bytes + 255) & ~(size_t)255;
    return r;
  };
  float*  dinv    = (float*) carve((size_t)N * 4);
  int*    cnt     = (int*)   carve((size_t)N * 4);
  int*    row_ptr = (int*)   carve((size_t)N * 4);
  int*    bsum    = (int*)   carve(TPB * 4);
  int*    bscan   = (int*)   carve(TPB * 4);
  int*    head    = (int*)   carve((size_t)N * 4);
  int*    next    = (int*)   carve((size_t)E * 4);
  int2*   csr     = (int2*)  carve((size_t)E * 8);
  bf16*   x_bf    = (bf16*)  carve((size_t)N * D * 2);
  bf16*   axb     = (bf16*)  carve((size_t)N * D * 2);
  bf16*   out1    = (bf16*)  carve((size_t)N * H * 2);
  bf16*   h2      = (bf16*)  carve((size_t)N * D * 2);
  bf16*   yb      = (bf16*)  carve((size_t)N * D * 2);
  float2* stats   = (float2*)carve((size_t)N * 4 * 8);
  bf16*   W1T     = (bf16*)  carve((size_t)D * H * 2);
  bf16*   W2T     = (bf16*)  carve((size_t)H * D * 2);

  const int gN = (N + TPB - 1) / TPB;
  const int gE = (E + TPB - 1) / TPB;
  const int n4 = N * D / 4;
  const int nw = D * H;
  const int gP = (n4 + TPB - 1) / TPB;   // covers n4 > N > nw
  const int bpp = (N + 3) / 4;           // blocks per feature-slice pass

  k_prep<<<gP, TPB, 0, stream>>>(x, x_bf, W1, W1T, W2, W2T, head, N, n4, nw, D, H);
  k_link<<<gE, TPB, 0, stream>>>(dst, head, next, E);
  k_walk_deg<<<gN, TPB, 0, stream>>>(head, next, ew, dinv, cnt, bsum, N);
  k_scan_bsums<<<1, TPB, 0, stream>>>(bsum, bscan, gN);
  k_scan_fill<<<gN, TPB, 0, stream>>>(cnt, bscan, head, next, src, ew, dinv,
                                      row_ptr, csr, N);

  // layer 1: sliced aggregate-first, then MFMA GEMM + bias + relu (bf16 out)
  k_agg1_slice<<<bpp * 4, TPB, 0, stream>>>(x_bf, dinv, row_ptr, cnt, csr,
                                            axb, N, bpp);
  dim3 g1((N + 127) / 128, H / 64);
  k_gemm_mfma<<<g1, TPB, 0, stream>>>(axb, W1T, b1, 1, N, D, H, out1);

  // layer 2: MFMA GEMM (bf16 out), sliced agg (+bias,+stats), then LN
  dim3 g2((N + 127) / 128, D / 64);
  k_gemm_mfma<<<g2, TPB, 0, stream>>>(out1, W2T, nullptr, 0, N, H, D, h2);
  k_agg2_slice<<<bpp * 4, TPB, 0, stream>>>(h2, dinv, row_ptr, cnt, csr,
                                            b2, yb, stats, N, bpp);
  k_ln<<<(N + 3) / 4, TPB, 0, stream>>>(yb, stats, gamma, beta, out, N);
}

// Round 7
// 234.868 us; speedup vs baseline: 1.5184x; 1.5184x over previous
//
#include <hip/hip_runtime.h>

// ---------------------------------------------------------------------------
// 2-layer GCN + LayerNorm on MI355X (gfx950), bf16 MFMA GEMMs.
//   Graph build via per-dst linked list (1 atomic/edge), fused walks+scan.
//   Layer 1 aggregate-first:  ax = A_norm @ x_bf16   -> out1 = relu(ax@W1+b1)
//   Layer 2 transform-first:  h2 = out1 @ W2 (bf16)  -> out = LN(agg(h2)+b2)
//   CSR entry packed to 4 B: [norm as bf16 (top 16 bits)] | [src as u16].
//   Aggregation: one wave per node, 64 lanes x bf16x2 = 256 B row per instr,
//   4-edge unroll. (R5 half-wave and R6 feature-sliced variants both measured
//   worse -- gather is fabric-BW-bound; bytes are the only lever.)
// ---------------------------------------------------------------------------

#define TPB 256

typedef __bf16 bf16;
typedef __bf16 bf16x2 __attribute__((ext_vector_type(2)));
typedef __bf16 bf16x4 __attribute__((ext_vector_type(4)));
typedef __bf16 bf16x8 __attribute__((ext_vector_type(8)));
typedef float  f32x4  __attribute__((ext_vector_type(4)));

// ---- prep: head=-1, x->bf16 (float4 granules), W1^T, W2^T (bf16) ----------
__global__ void k_prep(const float* __restrict__ x, bf16* __restrict__ x_bf,
                       const float* __restrict__ W1, bf16* __restrict__ W1T,
                       const float* __restrict__ W2, bf16* __restrict__ W2T,
                       int* __restrict__ head, int N, int n4, int nw,
                       int D, int H) {
  int i = blockIdx.x * TPB + threadIdx.x;
  if (i < N) head[i] = -1;
  if (i < nw) {
    int r1 = i / H, c1 = i % H;          // W1 [D][H] -> W1T [H][D]
    W1T[(size_t)c1 * D + r1] = (bf16)W1[i];
    int r2 = i / D, c2 = i % D;          // W2 [H][D] -> W2T [D][H]
    W2T[(size_t)c2 * H + r2] = (bf16)W2[i];
  }
  if (i < n4) {
    float4 v = reinterpret_cast<const float4*>(x)[i];
    bf16x4 o;
    o.x = (bf16)v.x; o.y = (bf16)v.y; o.z = (bf16)v.z; o.w = (bf16)v.w;
    reinterpret_cast<bf16x4*>(x_bf)[i] = o;
  }
}

__global__ void k_link(const int* __restrict__ dst, int* head,
                       int* __restrict__ next, int E) {
  int e = blockIdx.x * TPB + threadIdx.x;
  if (e < E) next[e] = atomicExch(&head[dst[e]], e);
}

// walk list: deg = 1 + sum(ew) -> dinv, cnt; fused per-block reduce -> bsum
__global__ void k_walk_deg(const int* __restrict__ head, const int* __restrict__ next,
                           const float* __restrict__ ew, float* __restrict__ dinv,
                           int* __restrict__ cnt, int* __restrict__ bsum, int N) {
  __shared__ int sm[TPB];
  int i = blockIdx.x * TPB + threadIdx.x;
  int c = 0;
  if (i < N) {
    float d = 1.0f;   // self-loop weight
    int h = head[i];
    while (h >= 0) {
      d += ew[h];
      ++c;
      h = next[h];
    }
    dinv[i] = rsqrtf(d);
    cnt[i] = c;
  }
  sm[threadIdx.x] = c;
  __syncthreads();
  for (int s = TPB / 2; s > 0; s >>= 1) {
    if (threadIdx.x < s) sm[threadIdx.x] += sm[threadIdx.x + s];
    __syncthreads();
  }
  if (threadIdx.x == 0) bsum[blockIdx.x] = sm[0];
}

__global__ void k_scan_bsums(const int* __restrict__ bsum, int* bscan, int nb) {
  __shared__ int sm[TPB];
  int t = threadIdx.x;
  int v = (t < nb) ? bsum[t] : 0;
  sm[t] = v;
  __syncthreads();
  for (int off = 1; off < TPB; off <<= 1) {
    int add = (t >= off) ? sm[t - off] : 0;
    __syncthreads();
    sm[t] += add;
    __syncthreads();
  }
  if (t < nb) bscan[t] = sm[t] - v;   // exclusive
}

// in-block scan of cnt -> row_ptr, then walk list filling packed {norm|src}
__global__ void k_scan_fill(const int* __restrict__ cnt, const int* __restrict__ bscan,
                            const int* __restrict__ head, const int* __restrict__ next,
                            const int* __restrict__ src, const float* __restrict__ ew,
                            const float* __restrict__ dinv,
                            int* __restrict__ row_ptr, unsigned int* __restrict__ csr,
                            int N) {
  __shared__ int sm[TPB];
  int t = threadIdx.x;
  int i = blockIdx.x * TPB + t;
  int v = (i < N) ? cnt[i] : 0;
  sm[t] = v;
  __syncthreads();
  for (int off = 1; off < TPB; off <<= 1) {
    int add = (t >= off) ? sm[t - off] : 0;
    __syncthreads();
    sm[t] += add;
    __syncthreads();
  }
  if (i < N) {
    int pos = bscan[blockIdx.x] + sm[t] - v;
    row_ptr[i] = pos;
    float di = dinv[i];
    int h = head[i];
    while (h >= 0) {
      int s = src[h];
      float nrm = dinv[s] * ew[h] * di;
      unsigned int nb = __float_as_uint((float)(bf16)nrm) & 0xFFFF0000u;
      csr[pos++] = nb | (unsigned int)s;   // src < 65536
      h = next[h];
    }
  }
}

// ---- bf16 MFMA GEMM, no LDS: C[M,NC] = A[M,K] @ BT[NC,K]^T (+bias,+relu) --
// Block: 256 thr / 4 waves; BM=128 (wave w: rows 32w..32w+31), BN=64.
// Frag layout (16x16x32): elem j of lane l -> k = 8*(l>>4)+j, m/n = l&15.
// C/D: col = l&15, row = 4*(l>>4)+reg  [m89-verified].
__global__ __launch_bounds__(256) void k_gemm_mfma(
    const bf16* __restrict__ A, const bf16* __restrict__ BT,
    const float* __restrict__ bias, int relu, int M, int K, int NC,
    bf16* __restrict__ Cb) {
  const int l = threadIdx.x & 63, w = threadIdx.x >> 6;
  const int c = l & 15, g = l >> 4;
  const int m0 = blockIdx.x * 128 + w * 32;
  const int n0 = blockIdx.y * 64;

  int ra0 = m0 + c;       if (ra0 >= M) ra0 = M - 1;
  int ra1 = m0 + 16 + c;  if (ra1 >= M) ra1 = M - 1;
  const bf16* pa0 = A + (size_t)ra0 * K + g * 8;
  const bf16* pa1 = A + (size_t)ra1 * K + g * 8;
  const bf16* pb0 = BT + (size_t)(n0 + c) * K + g * 8;

  f32x4 acc[2][4] = {};
  for (int k0 = 0; k0 < K; k0 += 32) {
    bf16x8 a0 = *reinterpret_cast<const bf16x8*>(pa0 + k0);
    bf16x8 a1 = *reinterpret_cast<const bf16x8*>(pa1 + k0);
    bf16x8 b0 = *reinterpret_cast<const bf16x8*>(pb0 + k0);
    bf16x8 b1 = *reinterpret_cast<const bf16x8*>(pb0 + (size_t)16 * K + k0);
    bf16x8 b2 = *reinterpret_cast<const bf16x8*>(pb0 + (size_t)32 * K + k0);
    bf16x8 b3 = *reinterpret_cast<const bf16x8*>(pb0 + (size_t)48 * K + k0);
    acc[0][0] = __builtin_amdgcn_mfma_f32_16x16x32_bf16(a0, b0, acc[0][0], 0, 0, 0);
    acc[1][0] = __builtin_amdgcn_mfma_f32_16x16x32_bf16(a1, b0, acc[1][0], 0, 0, 0);
    acc[0][1] = __builtin_amdgcn_mfma_f32_16x16x32_bf16(a0, b1, acc[0][1], 0, 0, 0);
    acc[1][1] = __builtin_amdgcn_mfma_f32_16x16x32_bf16(a1, b1, acc[1][1], 0, 0, 0);
    acc[0][2] = __builtin_amdgcn_mfma_f32_16x16x32_bf16(a0, b2, acc[0][2], 0, 0, 0);
    acc[1][2] = __builtin_amdgcn_mfma_f32_16x16x32_bf16(a1, b2, acc[1][2], 0, 0, 0);
    acc[0][3] = __builtin_amdgcn_mfma_f32_16x16x32_bf16(a0, b3, acc[0][3], 0, 0, 0);
    acc[1][3] = __builtin_amdgcn_mfma_f32_16x16x32_bf16(a1, b3, acc[1][3], 0, 0, 0);
  }

#pragma unroll
  for (int mi = 0; mi < 2; ++mi) {
    int rbase = m0 + mi * 16 + g * 4;
#pragma unroll
    for (int ni = 0; ni < 4; ++ni) {
      int col = n0 + ni * 16 + c;
      float bv = bias ? bias[col] : 0.0f;
      f32x4 v = acc[mi][ni];
#pragma unroll
      for (int r = 0; r < 4; ++r) {
        int row = rbase + r;
        if (row < M) {
          float o = v[r] + bv;
          if (relu) o = fmaxf(o, 0.0f);
          Cb[(size_t)row * NC + col] = (bf16)o;
        }
      }
    }
  }
}

// ---- agg layer 1: F=128 bf16 rows, one wave/node, 4-edge unroll -----------
__global__ __launch_bounds__(256) void k_agg_x(
    const bf16* __restrict__ h, const float* __restrict__ dinv,
    const int* __restrict__ row_ptr, const int* __restrict__ cnt,
    const unsigned int* __restrict__ csr, bf16* __restrict__ out, int N) {
  const int F = 128;
  int wid = threadIdx.x >> 6, lane = threadIdx.x & 63;
  int node = blockIdx.x * 4 + wid;
  if (node >= N) return;
  float di = dinv[node];
  float sw = di * di;
  int c2 = lane << 1;
  bf16x2 hv = *reinterpret_cast<const bf16x2*>(h + (size_t)node * F + c2);
  float ax = sw * (float)hv.x, ay = sw * (float)hv.y;
  const unsigned int* cp = csr + row_ptr[node];
  int n = cnt[node];
  int j = 0;
  for (; j + 4 <= n; j += 4) {
    unsigned int e0 = cp[j], e1 = cp[j + 1], e2 = cp[j + 2], e3 = cp[j + 3];
    bf16x2 v0 = *reinterpret_cast<const bf16x2*>(h + (size_t)(e0 & 0xFFFFu) * F + c2);
    bf16x2 v1 = *reinterpret_cast<const bf16x2*>(h + (size_t)(e1 & 0xFFFFu) * F + c2);
    bf16x2 v2 = *reinterpret_cast<const bf16x2*>(h + (size_t)(e2 & 0xFFFFu) * F + c2);
    bf16x2 v3 = *reinterpret_cast<const bf16x2*>(h + (size_t)(e3 & 0xFFFFu) * F + c2);
    float w0 = __uint_as_float(e0 & 0xFFFF0000u);
    float w1 = __uint_as_float(e1 & 0xFFFF0000u);
    float w2 = __uint_as_float(e2 & 0xFFFF0000u);
    float w3 = __uint_as_float(e3 & 0xFFFF0000u);
    ax += w0 * (float)v0.x + w1 * (float)v1.x + w2 * (float)v2.x + w3 * (float)v3.x;
    ay += w0 * (float)v0.y + w1 * (float)v1.y + w2 * (float)v2.y + w3 * (float)v3.y;
  }
  for (; j < n; ++j) {
    unsigned int e = cp[j];
    float w = __uint_as_float(e & 0xFFFF0000u);
    bf16x2 v = *reinterpret_cast<const bf16x2*>(h + (size_t)(e & 0xFFFFu) * F + c2);
    ax += w * (float)v.x; ay += w * (float)v.y;
  }
  bf16x2 o; o.x = (bf16)ax; o.y = (bf16)ay;
  *reinterpret_cast<bf16x2*>(out + (size_t)node * F + c2) = o;
}

// ---- agg layer 2 (bf16 in) + bias + fused LayerNorm, fp32 out -------------
__global__ __launch_bounds__(256) void k_agg2_ln(
    const bf16* __restrict__ h, const float* __restrict__ dinv,
    const int* __restrict__ row_ptr, const int* __restrict__ cnt,
    const unsigned int* __restrict__ csr, const float* __restrict__ b2,
    const float* __restrict__ gamma, const float* __restrict__ beta,
    float* __restrict__ out, int N) {
  const int F = 128;
  int wid = threadIdx.x >> 6, lane = threadIdx.x & 63;
  int node = blockIdx.x * 4 + wid;
  if (node >= N) return;
  float di = dinv[node];
  float sw = di * di;
  int c2 = lane << 1;
  float2 bb = *reinterpret_cast<const float2*>(b2 + c2);
  bf16x2 hv = *reinterpret_cast<const bf16x2*>(h + (size_t)node * F + c2);
  float ax = bb.x + sw * (float)hv.x, ay = bb.y + sw * (float)hv.y;
  const unsigned int* cp = csr + row_ptr[node];
  int n = cnt[node];
  int j = 0;
  for (; j + 4 <= n; j += 4) {
    unsigned int e0 = cp[j], e1 = cp[j + 1], e2 = cp[j + 2], e3 = cp[j + 3];
    bf16x2 v0 = *reinterpret_cast<const bf16x2*>(h + (size_t)(e0 & 0xFFFFu) * F + c2);
    bf16x2 v1 = *reinterpret_cast<const bf16x2*>(h + (size_t)(e1 & 0xFFFFu) * F + c2);
    bf16x2 v2 = *reinterpret_cast<const bf16x2*>(h + (size_t)(e2 & 0xFFFFu) * F + c2);
    bf16x2 v3 = *reinterpret_cast<const bf16x2*>(h + (size_t)(e3 & 0xFFFFu) * F + c2);
    float w0 = __uint_as_float(e0 & 0xFFFF0000u);
    float w1 = __uint_as_float(e1 & 0xFFFF0000u);
    float w2 = __uint_as_float(e2 & 0xFFFF0000u);
    float w3 = __uint_as_float(e3 & 0xFFFF0000u);
    ax += w0 * (float)v0.x + w1 * (float)v1.x + w2 * (float)v2.x + w3 * (float)v3.x;
    ay += w0 * (float)v0.y + w1 * (float)v1.y + w2 * (float)v2.y + w3 * (float)v3.y;
  }
  for (; j < n; ++j) {
    unsigned int e = cp[j];
    float w = __uint_as_float(e & 0xFFFF0000u);
    bf16x2 v = *reinterpret_cast<const bf16x2*>(h + (size_t)(e & 0xFFFFu) * F + c2);
    ax += w * (float)v.x; ay += w * (float)v.y;
  }
  // LayerNorm across the wave (128 values = 64 lanes x 2)
  float s  = ax + ay;
  float ss = ax * ax + ay * ay;
  for (int m = 32; m > 0; m >>= 1) {
    s  += __shfl_xor(s, m, 64);
    ss += __shfl_xor(ss, m, 64);
  }
  float mu  = s * (1.0f / 128.0f);
  float var = ss * (1.0f / 128.0f) - mu * mu;
  float inv = rsqrtf(var + 1e-5f);
  float2 g  = *reinterpret_cast<const float2*>(gamma + c2);
  float2 be = *reinterpret_cast<const float2*>(beta + c2);
  float2 o;
  o.x = (ax - mu) * inv * g.x + be.x;
  o.y = (ay - mu) * inv * g.y + be.y;
  *reinterpret_cast<float2*>(out + (size_t)node * F + c2) = o;
}

extern "C" void kernel_launch(void* const* d_in, const int* in_sizes, int n_in,
                              void* d_out, int out_size, void* d_ws, size_t ws_size,
                              hipStream_t stream) {
  const float* x     = (const float*)d_in[0];
  const int*   ei    = (const int*)d_in[1];
  const float* ew    = (const float*)d_in[2];
  const float* W1    = (const float*)d_in[3];
  const float* b1    = (const float*)d_in[4];
  const float* W2    = (const float*)d_in[5];
  const float* b2    = (const float*)d_in[6];
  const float* gamma = (const float*)d_in[7];
  const float* beta  = (const float*)d_in[8];
  float* out = (float*)d_out;

  const int D = 128, H = 256;
  const int N = in_sizes[0] / D;       // 50000
  const int E = in_sizes[2];           // 800000
  const int* src = ei;
  const int* dst = ei + E;

  // workspace carve-up (256B aligned)
  char* p = (char*)d_ws;
  auto carve = [&](size_t bytes) -> void* {
    void* r = (void*)p;
    p += (bytes + 255) & ~(size_t)255;
    return r;
  };
  float*        dinv    = (float*)carve((size_t)N * 4);
  int*          cnt     = (int*)  carve((size_t)N * 4);
  int*          row_ptr = (int*)  carve((size_t)N * 4);
  int*          bsum    = (int*)  carve(TPB * 4);
  int*          bscan   = (int*)  carve(TPB * 4);
  int*          head    = (int*)  carve((size_t)N * 4);
  int*          next    = (int*)  carve((size_t)E * 4);
  unsigned int* csr     = (unsigned int*)carve((size_t)E * 4);
  bf16*         x_bf    = (bf16*) carve((size_t)N * D * 2);
  bf16*         axb     = (bf16*) carve((size_t)N * D * 2);
  bf16*         out1    = (bf16*) carve((size_t)N * H * 2);
  bf16*         h2      = (bf16*) carve((size_t)N * D * 2);
  bf16*         W1T     = (bf16*) carve((size_t)D * H * 2);
  bf16*         W2T     = (bf16*) carve((size_t)H * D * 2);

  const int gN = (N + TPB - 1) / TPB;
  const int gE = (E + TPB - 1) / TPB;
  const int n4 = N * D / 4;
  const int nw = D * H;
  const int gP = (n4 + TPB - 1) / TPB;   // covers n4 > N > nw

  k_prep<<<gP, TPB, 0, stream>>>(x, x_bf, W1, W1T, W2, W2T, head, N, n4, nw, D, H);
  k_link<<<gE, TPB, 0, stream>>>(dst, head, next, E);
  k_walk_deg<<<gN, TPB, 0, stream>>>(head, next, ew, dinv, cnt, bsum, N);
  k_scan_bsums<<<1, TPB, 0, stream>>>(bsum, bscan, gN);
  k_scan_fill<<<gN, TPB, 0, stream>>>(cnt, bscan, head, next, src, ew, dinv,
                                      row_ptr, csr, N);

  // layer 1: aggregate-first, then MFMA GEMM + bias + relu (bf16 out)
  k_agg_x<<<(N + 3) / 4, TPB, 0, stream>>>(x_bf, dinv, row_ptr, cnt, csr, axb, N);
  dim3 g1((N + 127) / 128, H / 64);
  k_gemm_mfma<<<g1, TPB, 0, stream>>>(axb, W1T, b1, 1, N, D, H, out1);

  // layer 2: MFMA GEMM (bf16 out), then agg + bias + fused LN (fp32 out)
  dim3 g2((N + 127) / 128, D / 64);
  k_gemm_mfma<<<g2, TPB, 0, stream>>>(out1, W2T, nullptr, 0, N, H, D, h2);
  k_agg2_ln<<<(N + 3) / 4, TPB, 0, stream>>>(h2, dinv, row_ptr, cnt, csr,
                                             b2, gamma, beta, out, N);
}